// Round 2
// baseline (187.930 us; speedup 1.0000x reference)
//
#include <hip/hip_runtime.h>
#include <math.h>

typedef unsigned short ushort_t;
typedef unsigned int uint_t;
typedef __attribute__((ext_vector_type(4))) float f32x4;
typedef __attribute__((ext_vector_type(2))) float f32x2;

#define WSTRIDE 132   // dwords; 528B rows: 16B-aligned, conflict-free b128 reads

// ---------- dtype-generic access ----------
__device__ __forceinline__ float bf2f(ushort_t u){
    union { uint_t i; float f; } v; v.i = ((uint_t)u) << 16; return v.f;
}
__device__ __forceinline__ ushort_t f2bf(float f){
    union { float f; uint_t i; } v; v.f = f;
    uint_t x = v.i;
    return (ushort_t)((x + 0x7FFFu + ((x >> 16) & 1u)) >> 16);  // RNE
}
template<bool F32> __device__ __forceinline__ float ld1(const void* p, int i){
    if constexpr (F32) return ((const float*)p)[i];
    else               return bf2f(((const ushort_t*)p)[i]);
}
template<bool F32> __device__ __forceinline__ f32x2 ld2(const void* p, int i){ // i even
    if constexpr (F32) return *(const f32x2*)((const float*)p + i);
    else {
        uint_t u = *(const uint_t*)(((const ushort_t*)p) + i);
        return (f32x2){ bf2f((ushort_t)(u & 0xFFFFu)), bf2f((ushort_t)(u >> 16)) };
    }
}
template<bool F32> __device__ __forceinline__ void st1(void* p, int i, float v){
    if constexpr (F32) ((float*)p)[i] = v;
    else               ((ushort_t*)p)[i] = f2bf(v);
}
template<bool F32> __device__ __forceinline__ void* optr(void* out, int elem_off){
    if constexpr (F32) return (void*)(((float*)out) + elem_off);
    else               return (void*)(((ushort_t*)out) + elem_off);
}

// ---------- helpers ----------
__device__ __forceinline__ float wsum(float v){
    #pragma unroll
    for (int off = 32; off > 0; off >>= 1) v += __shfl_xor(v, off, 64);
    return v;
}
__device__ __forceinline__ float gelu_f(float x){
    return 0.5f * x * (1.0f + erff(x * 0.7071067811865476f));
}

template<int R>
__device__ __forceinline__ void matvecR(const float* WT, const float* xl,
                                        int lane, float (&acc)[R][2]){
    const float* w0p = WT + lane * WSTRIDE;
    const float* w1p = WT + (lane + 64) * WSTRIDE;
    #pragma unroll 4
    for (int fb = 0; fb < 128; fb += 4){
        f32x4 w0 = *(const f32x4*)(w0p + fb);
        f32x4 w1 = *(const f32x4*)(w1p + fb);
        #pragma unroll
        for (int r = 0; r < R; ++r){
            f32x4 xv = *(const f32x4*)(xl + (r << 7) + fb);
            acc[r][0] = fmaf(xv[0], w0[0], acc[r][0]);
            acc[r][0] = fmaf(xv[1], w0[1], acc[r][0]);
            acc[r][0] = fmaf(xv[2], w0[2], acc[r][0]);
            acc[r][0] = fmaf(xv[3], w0[3], acc[r][0]);
            acc[r][1] = fmaf(xv[0], w1[0], acc[r][1]);
            acc[r][1] = fmaf(xv[1], w1[1], acc[r][1]);
            acc[r][1] = fmaf(xv[2], w1[2], acc[r][1]);
            acc[r][1] = fmaf(xv[3], w1[3], acc[r][1]);
        }
    }
}

// ---------- dtype detector: low halves of f32 words are random-exponent garbage ----------
__global__ void k_detect(const void* W1, int* flag){
    const ushort_t* u = (const ushort_t*)W1;
    ushort_t x = u[2 * threadIdx.x];           // bf16: element 2*tid (sane); f32: low mantissa half (random)
    int e = (x >> 7) & 0xFF;
    int sane = (e >= 90 && e <= 127) ? 1 : 0;  // |val| in [~2^-37, 2): always true for W1 bf16 data
    unsigned long long m = __ballot(sane);
    if (threadIdx.x == 0) *flag = (__popcll(m) >= 48) ? 0 : 1;   // 1 => float32 inputs
}

// ---------- K0: combined weights (constant-adjacency fold) ----------
template<bool F32>
__device__ __forceinline__ void prep_body(const void* chw, const void* sW1,
                                          float* Wx, float* Wsv, float* sW1b){
    int i = blockIdx.x * 256 + threadIdx.x;          // 16384 total
    const float c1  = 0.5000000004166667f;           // 1/s, s = 1+6u, u = 1/(6+1e-8)
    const float c2  = 0.2500000004166667f;           // c1^2
    const float a   = 0.08333333326388889f;          // u/s
    const float a1c = 0.12499999993055555f;          // a*(1+c1)
    const float u   = 0.16666666638888889f;
    float w0 = ld1<F32>(chw, i);
    float w1 = ld1<F32>(chw, 16384 + i);
    float w2 = ld1<F32>(chw, 32768 + i);
    Wx[i]   = w0 + c1 * w1 + c2 * w2;
    Wsv[i]  = a * w1 + a1c * w2;
    sW1b[i] = u * ld1<F32>(sW1, 16384 + i);
}
__global__ void k_prep(const int* flag, const void* chw, const void* sW1,
                       float* Wx, float* Wsv, float* sW1b){
    if (*flag) prep_body<true >(chw, sW1, Wx, Wsv, sW1b);
    else       prep_body<false>(chw, sW1, Wx, Wsv, sW1b);
}

// ---------- adj output: constant 1/(6+1e-8) ----------
__global__ void k_adj(const int* flag, void* out){
    int i = blockIdx.x * 256 + threadIdx.x;          // 294912 threads
    if (*flag){
        float* adj = ((float*)out) + 1048576;
        adj[i] = 0.166666672f;                       // f32(1/(6+1e-8)) == f32(1/6)
    } else {
        uint_t* adj = (uint_t*)(((ushort_t*)out) + 1048576);
        if (i < 147456) adj[i] = 0x3E2B3E2Bu;        // bf16(1/6) x2
    }
}

// ---------- K1: fe_proj = gelu(LN(x@W1+b1)); S = sum over 6 nodes ----------
template<bool F32>
__device__ __forceinline__ void fe_body(const void* X_de, const void* W1, const void* b1,
                                        const void* lng, const void* lnb,
                                        void* out, float* S, float* WT, float* XLs){
    const int tid = threadIdx.x;
    for (int i = tid; i < 16384; i += 256){
        int f = i >> 7, h = i & 127;
        WT[h * WSTRIDE + f] = ld1<F32>(W1, i);
    }
    const int wave = tid >> 6, lane = tid & 63;
    const int g = blockIdx.x * 4 + wave;             // group = b*T + t
    const int b = g >> 7, t = g & 127;
    float* xl = XLs + wave * 768;
    #pragma unroll
    for (int c = 0; c < 6; ++c){
        int idx = ((((b * 6 + c) << 7) + t) << 7) + 2 * lane;   // X_de[b][c][t][:]
        *(f32x2*)(xl + (c << 7) + 2 * lane) = ld2<F32>(X_de, idx);
    }
    __syncthreads();
    const int h0 = lane, h1 = lane + 64;
    float acc[6][2];
    #pragma unroll
    for (int r = 0; r < 6; ++r){ acc[r][0] = 0.f; acc[r][1] = 0.f; }
    matvecR<6>(WT, xl, lane, acc);
    float bb0 = ld1<F32>(b1, h0),  bb1 = ld1<F32>(b1, h1);
    float gg0 = ld1<F32>(lng, h0), gg1 = ld1<F32>(lng, h1);
    float be0 = ld1<F32>(lnb, h0), be1 = ld1<F32>(lnb, h1);
    void* Xn = optr<F32>(out, 1343488);
    float S0 = 0.f, S1 = 0.f;
    #pragma unroll
    for (int c = 0; c < 6; ++c){
        float a0 = acc[c][0] + bb0, a1 = acc[c][1] + bb1;
        float sm = wsum(a0 + a1);
        float sq = wsum(a0 * a0 + a1 * a1);
        float m = sm * 0.0078125f;
        float var = sq * 0.0078125f - m * m;
        float rstd = rsqrtf(var + 1e-5f);
        float y0 = gelu_f((a0 - m) * rstd * gg0 + be0);
        float y1 = gelu_f((a1 - m) * rstd * gg1 + be1);
        S0 += y0; S1 += y1;
        int ro = (g * 6 + c) << 7;
        st1<F32>(Xn, ro + h0, y0);
        st1<F32>(Xn, ro + h1, y1);
    }
    S[(g << 7) + h0] = S0;
    S[(g << 7) + h1] = S1;
}
__global__ __launch_bounds__(256, 2)
void k_fe(const int* flag, const void* X_de, const void* W1, const void* b1,
          const void* lng, const void* lnb, void* out, float* S){
    __shared__ float WT[128 * WSTRIDE];
    __shared__ float XL[4][6 * 128];
    if (*flag) fe_body<true >(X_de, W1, b1, lng, lnb, out, S, WT, &XL[0][0]);
    else       fe_body<false>(X_de, W1, b1, lng, lnb, out, S, WT, &XL[0][0]);
}

// ---------- small matvec over 8192 rows, IN PLACE: SB[r] = SB[r]@Wf + bias ----------
template<bool F32>
__device__ __forceinline__ void mv_body(float* SB, const float* Wf, const void* bias,
                                        float* WT, float* XLs){
    const int tid = threadIdx.x;
    for (int i = tid; i < 16384; i += 256){
        int f = i >> 7, h = i & 127;
        WT[h * WSTRIDE + f] = Wf[i];
    }
    const int wave = tid >> 6, lane = tid & 63;
    const int r0 = (blockIdx.x * 4 + wave) * 4;
    float* xl = XLs + wave * 512;
    #pragma unroll
    for (int r = 0; r < 4; ++r)
        *(f32x2*)(xl + (r << 7) + 2 * lane) = *(const f32x2*)(SB + ((r0 + r) << 7) + 2 * lane);
    __syncthreads();
    float acc[4][2];
    #pragma unroll
    for (int r = 0; r < 4; ++r){ acc[r][0] = 0.f; acc[r][1] = 0.f; }
    matvecR<4>(WT, xl, lane, acc);
    float b0v = ld1<F32>(bias, lane), b1v = ld1<F32>(bias, lane + 64);
    #pragma unroll
    for (int r = 0; r < 4; ++r){
        SB[((r0 + r) << 7) + lane]      = acc[r][0] + b0v;
        SB[((r0 + r) << 7) + lane + 64] = acc[r][1] + b1v;
    }
}
__global__ __launch_bounds__(256, 2)
void k_mv(const int* flag, float* SB, const float* Wf, const void* bias){
    __shared__ float WT[128 * WSTRIDE];
    __shared__ float XL[4][4 * 128];
    if (*flag) mv_body<true >(SB, Wf, bias, WT, &XL[0][0]);
    else       mv_body<false>(SB, Wf, bias, WT, &XL[0][0]);
}

// ---------- K3: cheb: g = LN(Xn@Wx + T2[group]); Sg = sum over nodes (in place over SB) ----------
template<bool F32>
__device__ __forceinline__ void cheb_body(void* out, const float* Wx, float* SB,
                                          const void* cg, const void* cbn,
                                          float* WT, float* XLs){
    const int tid = threadIdx.x;
    for (int i = tid; i < 16384; i += 256){
        int f = i >> 7, h = i & 127;
        WT[h * WSTRIDE + f] = Wx[i];
    }
    const int wave = tid >> 6, lane = tid & 63;
    const int g = blockIdx.x * 4 + wave;
    float* xl = XLs + wave * 768;
    const void* Xn = optr<F32>(out, 1343488);
    #pragma unroll
    for (int c = 0; c < 6; ++c){
        int idx = ((g * 6 + c) << 7) + 2 * lane;
        *(f32x2*)(xl + (c << 7) + 2 * lane) = ld2<F32>(Xn, idx);
    }
    __syncthreads();
    const int h0 = lane, h1 = lane + 64;
    float acc[6][2];
    #pragma unroll
    for (int r = 0; r < 6; ++r){ acc[r][0] = 0.f; acc[r][1] = 0.f; }
    matvecR<6>(WT, xl, lane, acc);
    float t20 = SB[(g << 7) + h0], t21 = SB[(g << 7) + h1];  // T2 (includes cheb_b)
    float gg0 = ld1<F32>(cg, h0),  gg1 = ld1<F32>(cg, h1);
    float be0 = ld1<F32>(cbn, h0), be1 = ld1<F32>(cbn, h1);
    void* G = optr<F32>(out, 7634944);
    float S0 = 0.f, S1 = 0.f;
    #pragma unroll
    for (int c = 0; c < 6; ++c){
        float a0 = acc[c][0] + t20, a1 = acc[c][1] + t21;
        float sm = wsum(a0 + a1);
        float sq = wsum(a0 * a0 + a1 * a1);
        float m = sm * 0.0078125f;
        float var = sq * 0.0078125f - m * m;
        float rstd = rsqrtf(var + 1e-5f);
        float y0 = (a0 - m) * rstd * gg0 + be0;
        float y1 = (a1 - m) * rstd * gg1 + be1;
        S0 += y0; S1 += y1;
        int ro = (g * 6 + c) << 7;
        st1<F32>(G, ro + h0, y0);
        st1<F32>(G, ro + h1, y1);
    }
    SB[(g << 7) + h0] = S0;    // Sg overwrites T2 (same row, read already done)
    SB[(g << 7) + h1] = S1;
}
__global__ __launch_bounds__(256, 2)
void k_cheb(const int* flag, void* out, const float* Wx, float* SB,
            const void* cg, const void* cbn){
    __shared__ float WT[128 * WSTRIDE];
    __shared__ float XL[4][6 * 128];
    if (*flag) cheb_body<true >(out, Wx, SB, cg, cbn, WT, &XL[0][0]);
    else       cheb_body<false>(out, Wx, SB, cg, cbn, WT, &XL[0][0]);
}

// ---------- K5: satt: h=gelu(LN(g@sW1A + T4)); att=sigmoid(h@sW2+sb2); epoch=mean(g*att) ----------
template<bool F32>
__device__ __forceinline__ void satt_body(void* out, const void* sW1, const float* SB,
                                          const void* sg, const void* sb,
                                          const void* sW2, const void* sb2,
                                          float* WT, float* XLs){
    const int tid = threadIdx.x;
    for (int i = tid; i < 16384; i += 256){           // sW1 rows 0..127 only
        int f = i >> 7, h = i & 127;
        WT[h * WSTRIDE + f] = ld1<F32>(sW1, i);
    }
    const int wave = tid >> 6, lane = tid & 63;
    const int g = blockIdx.x * 4 + wave;
    float* xl = XLs + wave * 768;
    const void* G = optr<F32>(out, 7634944);
    #pragma unroll
    for (int c = 0; c < 6; ++c){
        int idx = ((g * 6 + c) << 7) + 2 * lane;
        *(f32x2*)(xl + (c << 7) + 2 * lane) = ld2<F32>(G, idx);
    }
    __syncthreads();
    const int h0 = lane, h1 = lane + 64;
    float acc[6][2];
    #pragma unroll
    for (int r = 0; r < 6; ++r){ acc[r][0] = 0.f; acc[r][1] = 0.f; }
    matvecR<6>(WT, xl, lane, acc);
    float t40 = SB[(g << 7) + h0], t41 = SB[(g << 7) + h1];  // T4 (includes sb1)
    float gg0 = ld1<F32>(sg, h0),  gg1 = ld1<F32>(sg, h1);
    float be0 = ld1<F32>(sb, h0),  be1 = ld1<F32>(sb, h1);
    float w20 = ld1<F32>(sW2, h0), w21 = ld1<F32>(sW2, h1);
    float sb2v = ld1<F32>(sb2, 0);
    float ep0 = 0.f, ep1 = 0.f;
    #pragma unroll
    for (int c = 0; c < 6; ++c){
        float a0 = acc[c][0] + t40, a1 = acc[c][1] + t41;
        float sm = wsum(a0 + a1);
        float sq = wsum(a0 * a0 + a1 * a1);
        float m = sm * 0.0078125f;
        float var = sq * 0.0078125f - m * m;
        float rstd = rsqrtf(var + 1e-5f);
        float y0 = gelu_f((a0 - m) * rstd * gg0 + be0);
        float y1 = gelu_f((a1 - m) * rstd * gg1 + be1);
        float z = wsum(y0 * w20 + y1 * w21) + sb2v;
        float att = 1.0f / (1.0f + expf(-z));
        ep0 = fmaf(xl[(c << 7) + h0], att, ep0);
        ep1 = fmaf(xl[(c << 7) + h1], att, ep1);
    }
    st1<F32>(out, (g << 7) + h0, ep0 * (1.0f / 6.0f));
    st1<F32>(out, (g << 7) + h1, ep1 * (1.0f / 6.0f));
}
__global__ __launch_bounds__(256, 2)
void k_satt(const int* flag, void* out, const void* sW1, const float* SB,
            const void* sg, const void* sb, const void* sW2, const void* sb2){
    __shared__ float WT[128 * WSTRIDE];
    __shared__ float XL[4][6 * 128];
    if (*flag) satt_body<true >(out, sW1, SB, sg, sb, sW2, sb2, WT, &XL[0][0]);
    else       satt_body<false>(out, sW1, SB, sg, sb, sW2, sb2, WT, &XL[0][0]);
}

// ---------- launcher ----------
extern "C" void kernel_launch(void* const* d_in, const int* in_sizes, int n_in,
                              void* d_out, int out_size, void* d_ws, size_t ws_size,
                              hipStream_t stream){
    const void* X_de = d_in[0];
    const void* W1   = d_in[1];
    const void* b1   = d_in[2];
    const void* ln1g = d_in[3];
    const void* ln1b = d_in[4];
    // d_in[5..8] (aw, ab, aln_g, aln_b) are mathematically dead: LN over a size-1 axis == aln_b,
    // so adj = softmax(const) = 1/(6+1e-8) regardless of data.
    const void* chw  = d_in[9];
    const void* chb  = d_in[10];
    const void* clng = d_in[11];
    const void* clnb = d_in[12];
    const void* sW1  = d_in[13];
    const void* sb1  = d_in[14];
    const void* slng = d_in[15];
    const void* slnb = d_in[16];
    const void* sW2  = d_in[17];
    const void* sb2  = d_in[18];

    float* ws   = (float*)d_ws;
    int*   flag = (int*)d_ws;              // ws[0]
    float* Wx   = ws + 64;                 // 16384
    float* Wsv  = ws + 64 + 16384;         // 16384
    float* sW1b = ws + 64 + 32768;         // 16384
    float* SB   = ws + 64 + 49152;         // 8192*128 f32 (S -> T2 -> Sg -> T4, in place)

    hipLaunchKernelGGL(k_detect, dim3(1),    dim3(64),  0, stream, W1, flag);
    hipLaunchKernelGGL(k_prep,   dim3(64),   dim3(256), 0, stream, flag, chw, sW1, Wx, Wsv, sW1b);
    hipLaunchKernelGGL(k_adj,    dim3(1152), dim3(256), 0, stream, flag, d_out);
    hipLaunchKernelGGL(k_fe,     dim3(2048), dim3(256), 0, stream, flag, X_de, W1, b1, ln1g, ln1b, d_out, SB);
    hipLaunchKernelGGL(k_mv,     dim3(512),  dim3(256), 0, stream, flag, SB, Wsv, chb);
    hipLaunchKernelGGL(k_cheb,   dim3(2048), dim3(256), 0, stream, flag, d_out, Wx, SB, clng, clnb);
    hipLaunchKernelGGL(k_mv,     dim3(512),  dim3(256), 0, stream, flag, SB, sW1b, sb1);
    hipLaunchKernelGGL(k_satt,   dim3(2048), dim3(256), 0, stream, flag, d_out, sW1, SB, slng, slnb, sW2, sb2);
}

// Round 3
// 82.784 us; speedup vs baseline: 2.2701x; 2.2701x over previous
//
#include <hip/hip_runtime.h>
#include <math.h>

typedef unsigned short u16;
typedef unsigned int u32;
typedef __attribute__((ext_vector_type(2))) float f32x2;
typedef __attribute__((ext_vector_type(4))) float f32x4;
typedef __attribute__((ext_vector_type(8))) short bf16x8;
typedef __attribute__((ext_vector_type(4))) u32 u32x4;

// adjacency-collapse constants: u = 1/(6+1e-8); s = 1+6u; c1=1/s; c2=c1^2; a=u/s; a1c=a*(1+c1)
#define U_CONST   0.16666666638888889f
#define C1_CONST  0.5000000004166667f
#define C2_CONST  0.2500000004166667f
#define A_CONST   0.08333333326388889f
#define A1C_CONST 0.12499999993055555f

__device__ __forceinline__ float bf2f(u16 u){ union{u32 i; float f;} v; v.i=((u32)u)<<16; return v.f; }
__device__ __forceinline__ u16 f2bf(float f){ union{float f; u32 i;} v; v.f=f; u32 x=v.i;
  return (u16)((x + 0x7FFFu + ((x>>16)&1u)) >> 16); }  // RNE
__device__ __forceinline__ float gelu_f(float x){ return 0.5f*x*(1.0f+erff(x*0.7071067811865476f)); }

// ---------- prep: combined weights, W^T, bf16, LDS-swizzled ----------
// layout: ushort idx = h*128 + (f ^ ((h&7)<<3)) holds W[f][h]
// slots: 0:W1  16384:Wx  32768:Wsv  49152:sW1a  65536:sW1b' (=u*sW1[128:])
__global__ void k_prep(const float* __restrict__ W1, const float* __restrict__ chw,
                       const float* __restrict__ sW1, u16* __restrict__ WT5){
  int i = blockIdx.x*256 + threadIdx.x;          // 16384
  int f = i >> 7, h = i & 127;
  int dst = (h<<7) + (f ^ ((h&7)<<3));
  float w0 = chw[i], w1 = chw[16384+i], w2 = chw[32768+i];
  WT5[dst]         = f2bf(W1[i]);
  WT5[16384+dst]   = f2bf(w0 + C1_CONST*w1 + C2_CONST*w2);
  WT5[32768+dst]   = f2bf(A_CONST*w1 + A1C_CONST*w2);
  WT5[49152+dst]   = f2bf(sW1[i]);
  WT5[65536+dst]   = f2bf(U_CONST*sW1[16384+i]);
}

// adj = softmax(const) = 1/(6+1e-8) everywhere (LN over size-1 axis kills the data dependence)
__global__ void k_adj(float* __restrict__ adj){
  adj[blockIdx.x*256 + threadIdx.x] = 0.16666667f;
}

// ---------- fused kernel helpers ----------
__device__ __forceinline__ void wcopy(u16* Wb, const u16* __restrict__ src, int tid){
  const u32x4* s = (const u32x4*)src;
  u32x4* d = (u32x4*)Wb;
  #pragma unroll
  for (int j=0;j<6;++j){ int idx = tid + 384*j; if (idx < 2048) d[idx] = s[idx]; }
}

// MFMA fragment read: row-major [row][k] bf16 LDS tile, 256B rows, XOR-swizzled
__device__ __forceinline__ bf16x8 frag(const u16* base, int row, int kt, int cq){
  int off = ((kt<<6) + (cq<<4)) ^ ((row&7)<<4);
  return *(const bf16x8*)((const char*)base + (row<<8) + off);
}

// full-width GEMM: wave computes rows [arow..arow+15] x all 128 cols, K=128
__device__ __forceinline__ void gemm8(const u16* Ab, const u16* Wb, f32x4 (&acc)[8],
                                      int arow, int cl, int cq){
  #pragma unroll
  for (int n=0;n<8;n++) acc[n] = (f32x4){0.f,0.f,0.f,0.f};
  #pragma unroll
  for (int kt=0;kt<4;kt++){
    bf16x8 af = frag(Ab, arow + cl, kt, cq);
    #pragma unroll
    for (int n=0;n<8;n++){
      bf16x8 bfr = frag(Wb, (n<<4)+cl, kt, cq);
      acc[n] = __builtin_amdgcn_mfma_f32_16x16x32_bf16(af, bfr, acc[n], 0, 0, 0);
    }
  }
}

// 16-group matvec: Tb[g][:] = Sb[g][:] @ Wb + bias  (ntiles split across 6 waves)
__device__ __forceinline__ void gemm_small(const u16* Sb, const u16* Wb, float* Tb,
                                           const float* bias, int w, int cl, int cq){
  f32x4 a0 = (f32x4){0.f,0.f,0.f,0.f}, a1 = (f32x4){0.f,0.f,0.f,0.f};
  int n0 = w, n1 = w + 6;
  #pragma unroll
  for (int kt=0;kt<4;kt++){
    bf16x8 af = frag(Sb, cl, kt, cq);
    a0 = __builtin_amdgcn_mfma_f32_16x16x32_bf16(af, frag(Wb,(n0<<4)+cl,kt,cq), a0, 0,0,0);
    if (w < 2)
      a1 = __builtin_amdgcn_mfma_f32_16x16x32_bf16(af, frag(Wb,(n1<<4)+cl,kt,cq), a1, 0,0,0);
  }
  {
    float cb = bias[(n0<<4)+cl];
    #pragma unroll
    for (int j=0;j<4;j++) Tb[(((cq<<2)+j)<<7) + (n0<<4)+cl] = a0[j] + cb;
  }
  if (w < 2){
    float cb = bias[(n1<<4)+cl];
    #pragma unroll
    for (int j=0;j<4;j++) Tb[(((cq<<2)+j)<<7) + (n1<<4)+cl] = a1[j] + cb;
  }
}

// in-wave LayerNorm over 128 cols (rows live in-wave: 4 rows/lane, 16 lanes/row-group)
template<bool GELU>
__device__ __forceinline__ void ln_rows(f32x4 (&acc)[8], const float* gvec, const float* bvec, int cl){
  float sm[4]={0,0,0,0}, sq[4]={0,0,0,0};
  #pragma unroll
  for (int n=0;n<8;n++)
    #pragma unroll
    for (int j=0;j<4;j++){ float x = acc[n][j]; sm[j]+=x; sq[j]+=x*x; }
  #pragma unroll
  for (int j=0;j<4;j++){
    #pragma unroll
    for (int off=1; off<16; off<<=1){ sm[j]+=__shfl_xor(sm[j],off); sq[j]+=__shfl_xor(sq[j],off); }
  }
  #pragma unroll
  for (int j=0;j<4;j++){
    float m = sm[j]*0.0078125f;
    float r = rsqrtf(sq[j]*0.0078125f - m*m + 1e-5f);
    sm[j]=m; sq[j]=r;
  }
  #pragma unroll
  for (int n=0;n<8;n++){
    float gg = gvec[(n<<4)+cl], be = bvec[(n<<4)+cl];
    #pragma unroll
    for (int j=0;j<4;j++){
      float y = (acc[n][j]-sm[j])*sq[j]*gg + be;
      acc[n][j] = GELU ? gelu_f(y) : y;
    }
  }
}

// store rows to global f32 (paired f32x2) + packed bf16 into Ab (swizzled)
__device__ __forceinline__ void store_rows(const f32x4 (&acc)[8], float* __restrict__ gdst,
                                           u16* Ab, int w, int cl, int cq){
  #pragma unroll
  for (int n=0;n<8;n++)
    #pragma unroll
    for (int j=0;j<4;j++){
      int R = (w<<4)+(cq<<2)+j;
      float y = acc[n][j];
      float yo = __shfl_xor(y, 1);
      if (!(cl&1)){
        int col = (n<<4)+cl;
        *(f32x2*)(gdst + (size_t)R*128 + col) = (f32x2){y, yo};
        *(u32*)((char*)Ab + (R<<8) + ((col<<1) ^ ((R&7)<<4))) = (u32)f2bf(y) | ((u32)f2bf(yo)<<16);
      }
    }
}

// per-group sums of 6 node rows -> bf16 Sb (swizzled)
__device__ __forceinline__ void sbuild(const u16* Ab, u16* Sb, int tid){
  for (int idx = tid; idx < 2048; idx += 384){
    int g = idx >> 7, col = idx & 127;
    float s = 0.f;
    #pragma unroll
    for (int c=0;c<6;c++){ int r = 6*g+c; s += bf2f(Ab[(r<<7) + (col ^ ((r&7)<<3))]); }
    Sb[(g<<7) + (col ^ ((g&7)<<3))] = f2bf(s);
  }
}

// ---------- the fused pipeline: 16 groups (96 rows) per block, 6 waves ----------
__global__ __launch_bounds__(384, 3)
void k_fused(const float* __restrict__ X_de, const u16* __restrict__ WT5,
             const float* __restrict__ b1, const float* __restrict__ ln1g, const float* __restrict__ ln1b,
             const float* __restrict__ chb, const float* __restrict__ clng, const float* __restrict__ clnb,
             const float* __restrict__ sb1, const float* __restrict__ slng, const float* __restrict__ slnb,
             const float* __restrict__ sW2, const float* __restrict__ sb2p,
             float* __restrict__ out)
{
  __shared__ __align__(16) u16  Wb[128*128];   // 32KB current weight (bf16, swizzled W^T)
  __shared__ __align__(16) u16  Ab[96*128];    // 24KB X -> Xn -> g (bf16, swizzled)
  __shared__ __align__(16) u16  Sb[16*128];    // 4KB group sums (bf16, swizzled)
  __shared__ __align__(16) float Tb[16*128];   // 8KB T2 / T4 group biases
  __shared__ __align__(16) float vec[10*128];  // 5KB epilogue vectors
  __shared__ float attb[96];

  const int tid = threadIdx.x;
  const int w = tid >> 6, lane = tid & 63;
  const int cl = lane & 15, cq = lane >> 4;
  const int GB = blockIdx.x;
  const int g0 = GB << 4;
  const int Rb = (w<<4) + (cq<<2);

  if (tid < 128){
    vec[tid]      = b1[tid];   vec[128+tid]  = ln1g[tid]; vec[256+tid]  = ln1b[tid];
    vec[384+tid]  = chb[tid];  vec[512+tid]  = clng[tid]; vec[640+tid]  = clnb[tid];
    vec[768+tid]  = sb1[tid];  vec[896+tid]  = slng[tid]; vec[1024+tid] = slnb[tid];
    vec[1152+tid] = sW2[tid];
  }
  wcopy(Wb, WT5, tid);                                   // W1
  for (int r = w; r < 96; r += 6){                       // stage X (f32 -> bf16, swizzled)
    int grp = (r*342) >> 11, c = r - 6*grp;              // exact r/6 for r<96
    int g = g0 + grp, bb = g >> 7, tt = g & 127;
    const float* xp = X_de + ((size_t)((bb*6 + c)*128 + tt) << 7);
    f32x2 v = *(const f32x2*)(xp + 2*lane);
    *(u32*)((char*)Ab + (r<<8) + ((4*lane) ^ ((r&7)<<4))) = (u32)f2bf(v.x) | ((u32)f2bf(v.y)<<16);
  }
  __syncthreads();

  f32x4 acc[8];

  // ---- stage 1: Xn = gelu(LN(X@W1 + b1)) ----
  gemm8(Ab, Wb, acc, (w<<4), cl, cq);
  __syncthreads();
  wcopy(Wb, WT5 + 32768, tid);                           // Wsv
  #pragma unroll
  for (int n=0;n<8;n++){ float bv = vec[(n<<4)+cl];
    #pragma unroll
    for (int j=0;j<4;j++) acc[n][j] += bv; }
  ln_rows<true>(acc, vec+128, vec+256, cl);
  store_rows(acc, out + 1343488 + (size_t)GB*96*128, Ab, w, cl, cq);
  __syncthreads();
  sbuild(Ab, Sb, tid);                                   // S
  __syncthreads();
  gemm_small(Sb, Wb, Tb, vec+384, w, cl, cq);            // T2 = S@Wsv + cheb_b
  __syncthreads();
  wcopy(Wb, WT5 + 16384, tid);                           // Wx
  __syncthreads();

  // ---- stage 3: g = LN(Xn@Wx + T2) ----
  gemm8(Ab, Wb, acc, (w<<4), cl, cq);
  __syncthreads();
  wcopy(Wb, WT5 + 65536, tid);                           // sW1b'
  #pragma unroll
  for (int j=0;j<4;j++){
    int gl = ((Rb + j)*342) >> 11;
    #pragma unroll
    for (int n=0;n<8;n++) acc[n][j] += Tb[(gl<<7) + (n<<4)+cl];
  }
  ln_rows<false>(acc, vec+512, vec+640, cl);
  store_rows(acc, out + 7634944 + (size_t)GB*96*128, Ab, w, cl, cq);
  __syncthreads();
  sbuild(Ab, Sb, tid);                                   // Sg
  __syncthreads();
  gemm_small(Sb, Wb, Tb, vec+768, w, cl, cq);            // T4 = Sg@sW1b' + sb1
  __syncthreads();
  wcopy(Wb, WT5 + 49152, tid);                           // sW1a
  __syncthreads();

  // ---- stage 5: h = gelu(LN(g@sW1a + T4)); att = sigmoid(h@sW2+sb2); epoch ----
  gemm8(Ab, Wb, acc, (w<<4), cl, cq);
  {
    #pragma unroll
    for (int j=0;j<4;j++){
      int gl = ((Rb + j)*342) >> 11;
      #pragma unroll
      for (int n=0;n<8;n++) acc[n][j] += Tb[(gl<<7) + (n<<4)+cl];
    }
    ln_rows<true>(acc, vec+896, vec+1024, cl);
    float z[4] = {0,0,0,0};
    #pragma unroll
    for (int n=0;n<8;n++){ float wv = vec[1152+(n<<4)+cl];
      #pragma unroll
      for (int j=0;j<4;j++) z[j] += acc[n][j]*wv; }
    float sb2v = sb2p[0];
    #pragma unroll
    for (int j=0;j<4;j++){
      #pragma unroll
      for (int off=1; off<16; off<<=1) z[j] += __shfl_xor(z[j], off);
      z[j] = 1.0f/(1.0f + expf(-(z[j] + sb2v)));
    }
    if (cl == 0){
      #pragma unroll
      for (int j=0;j<4;j++) attb[Rb + j] = z[j];
    }
  }
  __syncthreads();
  for (int idx = tid; idx < 2048; idx += 384){
    int g = idx >> 7, col = idx & 127;
    float s = 0.f;
    #pragma unroll
    for (int c=0;c<6;c++){ int r = 6*g+c; s += attb[r]*bf2f(Ab[(r<<7)+(col ^ ((r&7)<<3))]); }
    out[(size_t)(g0+g)*128 + col] = s*(1.0f/6.0f);
  }
}

// ---------- launcher ----------
extern "C" void kernel_launch(void* const* d_in, const int* in_sizes, int n_in,
                              void* d_out, int out_size, void* d_ws, size_t ws_size,
                              hipStream_t stream){
  const float* X_de = (const float*)d_in[0];
  const float* W1   = (const float*)d_in[1];
  const float* b1   = (const float*)d_in[2];
  const float* ln1g = (const float*)d_in[3];
  const float* ln1b = (const float*)d_in[4];
  // d_in[5..8] (aw, ab, aln_g, aln_b) mathematically dead: LN over size-1 axis == aln_b
  const float* chw  = (const float*)d_in[9];
  const float* chb  = (const float*)d_in[10];
  const float* clng = (const float*)d_in[11];
  const float* clnb = (const float*)d_in[12];
  const float* sW1  = (const float*)d_in[13];
  const float* sb1  = (const float*)d_in[14];
  const float* slng = (const float*)d_in[15];
  const float* slnb = (const float*)d_in[16];
  const float* sW2  = (const float*)d_in[17];
  const float* sb2  = (const float*)d_in[18];

  float* out = (float*)d_out;
  u16* WT5 = (u16*)d_ws;   // 5 x 16384 bf16 = 160KB

  hipLaunchKernelGGL(k_prep,  dim3(64),   dim3(256), 0, stream, W1, chw, sW1, WT5);
  hipLaunchKernelGGL(k_adj,   dim3(1152), dim3(256), 0, stream, out + 1048576);
  hipLaunchKernelGGL(k_fused, dim3(512),  dim3(384), 0, stream,
                     X_de, WT5, b1, ln1g, ln1b, chb, clng, clnb,
                     sb1, slng, slnb, sW2, sb2, out);
}